// Round 6
// baseline (101.556 us; speedup 1.0000x reference)
//
#include <hip/hip_runtime.h>
#include <math.h>

typedef float f32x4 __attribute__((ext_vector_type(4)));
typedef float f32x2 __attribute__((ext_vector_type(2)));

// Data-parallel shape: thread = (sample, unit-pair). 16 threads/sample,
// 16 samples/block (256 thr), 1024 blocks -> 4096 waves = 4/SIMD, 4 blocks/CU.
// All cross-unit exchange is intra-wave LDS broadcast (samples never span waves).
__global__ __launch_bounds__(256, 4) void mnist_dp(
    const float* __restrict__ img, const float* __restrict__ Wff,
    const float* __restrict__ Wfb, const float* __restrict__ Wvel,
    const float* __restrict__ Wc1, const float* __restrict__ bc1,
    const float* __restrict__ Wc2, const float* __restrict__ bc2,
    float* __restrict__ out) {
  __shared__ float WffL[32 * 36], WfbL[32 * 36], Mds[32 * 36];
  __shared__ float r6L[16 * 36], snL[16 * 36], tdLs[16 * 36];
  __shared__ float ftL[16 * 132], hLd[16 * 68];

  const int t = threadIdx.x;
  const int s = t >> 4;                 // sample in block (0..15), wave-local (4/wave)
  const int p = t & 15;                 // thread in sample
  const int u0 = 2 * p, u1 = u0 + 1;    // owned units
  const int sg = blockIdx.x * 16 + s;   // global sample

  // ---- tap indices (never clipped: pos in [11.75, 771.25]) ----
  const float pos0 = 24.5f * (float)u0 + 11.75f;
  const float pos1 = 24.5f * (float)u1 + 11.75f;
  const int lo0 = (int)pos0, lo1 = (int)pos1;
  const float w0 = pos0 - (float)lo0, w1 = pos1 - (float)lo1;
  const int ta0 = (lo0 % 28) * 28 + lo0 / 28;
  const int tb0 = ((lo0 + 1) % 28) * 28 + (lo0 + 1) / 28;
  const int ta1 = (lo1 % 28) * 28 + lo1 / 28;
  const int tb1 = ((lo1 + 1) % 28) * 28 + (lo1 + 1) / 28;

  // ---- issue all global tap loads up front (8 independent scalars) ----
  const float* im = img + (size_t)sg * 784;
  const float a0 = im[lo0], a1 = im[lo0 + 1];
  const float b0 = im[lo1], b1 = im[lo1 + 1];
  const float c0 = im[ta0], c1 = im[tb0];
  const float d0 = im[ta1], d1 = im[tb1];
  const float2 wva = ((const float2*)Wvel)[u0];
  const float2 wvb = ((const float2*)Wvel)[u1];

  // ---- stage Wff/Wfb rows into LDS (stride 36: b128-aligned, bank-spread) ----
  {
    const int rj = t >> 3, c4 = (t & 7) * 4;
    f32x4 vff = *(const f32x4*)(Wff + rj * 32 + c4);
    f32x4 vfb = *(const f32x4*)(Wfb + rj * 32 + c4);
    *(f32x4*)(WffL + rj * 36 + c4) = vff;
    *(f32x4*)(WfbL + rj * 36 + c4) = vfb;
  }
  __syncthreads();

  // ---- cooperative M = Wff @ Wfb  (M[i][k] = sum_j Wff[i][j] * Wfb[j][k]) ----
  {
    const int i = t >> 3, k0 = (t & 7) * 4;
    float m0 = 0.f, m1 = 0.f, m2 = 0.f, m3 = 0.f;
#pragma unroll
    for (int j = 0; j < 32; ++j) {
      const float a = WffL[i * 36 + j];
      const f32x4 w4 = *(const f32x4*)(WfbL + j * 36 + k0);
      m0 += a * w4[0]; m1 += a * w4[1]; m2 += a * w4[2]; m3 += a * w4[3];
    }
    f32x4 m = {m0, m1, m2, m3};
    *(f32x4*)(Mds + i * 36 + k0) = m;
  }
  __syncthreads();

  // ---- own M rows into registers (64 VGPR) ----
  f32x4 M0[8], M1[8];
#pragma unroll
  for (int kb = 0; kb < 8; ++kb) {
    M0[kb] = *(const f32x4*)(Mds + u0 * 36 + kb * 4);
    M1[kb] = *(const f32x4*)(Mds + u1 * 36 + kb * 4);
  }

  // ---- interp -> sens/td, share across sample via LDS (intra-wave) ----
  const float sv0 = (a0 + (a1 - a0) * w0) * 80.0f;
  const float sv1 = (b0 + (b1 - b0) * w1) * 80.0f;
  const float tv0 = (c0 + (c1 - c0) * w0) * 40.0f;
  const float tv1 = (d0 + (d1 - d0) * w1) * 40.0f;
  { f32x2 v = {sv0, sv1}; *(f32x2*)(snL  + s * 36 + u0) = v; }
  { f32x2 v = {tv0, tv1}; *(f32x2*)(tdLs + s * 36 + u0) = v; }
  __builtin_amdgcn_wave_barrier();

  // ---- sff_i = Wff[i]·sens ; yfb_i = relu(Wfb[i]·td) ----
  float sf0 = 0.f, sf1 = 0.f, yb0 = 0.f, yb1 = 0.f;
#pragma unroll
  for (int jb = 0; jb < 8; ++jb) {
    const f32x4 s4 = *(const f32x4*)(snL  + s * 36 + jb * 4);
    const f32x4 t4 = *(const f32x4*)(tdLs + s * 36 + jb * 4);
    const f32x4 f0 = *(const f32x4*)(WffL + u0 * 36 + jb * 4);
    const f32x4 f1 = *(const f32x4*)(WffL + u1 * 36 + jb * 4);
    const f32x4 g0 = *(const f32x4*)(WfbL + u0 * 36 + jb * 4);
    const f32x4 g1 = *(const f32x4*)(WfbL + u1 * 36 + jb * 4);
#pragma unroll
    for (int c = 0; c < 4; ++c) {
      sf0 += f0[c] * s4[c]; sf1 += f1[c] * s4[c];
      yb0 += g0[c] * t4[c]; yb1 += g1[c] * t4[c];
    }
  }
  yb0 = fmaxf(yb0, 0.f); yb1 = fmaxf(yb1, 0.f);

  // ---- recurrence: y = relu(sff - M·r6); r6 += 0.1(-r6 + y + yfb + vin) ----
  float r0 = 0.f, r1 = 0.f, y0 = 0.f, y1 = 0.f, e0 = 0.f, e1 = 0.f;
  const float VX[3] = {0.2f, 0.0f, 0.15f};
  const float VY[3] = {0.0f, 0.2f, 0.15f};
#pragma unroll
  for (int v = 0; v < 3; ++v) {
    const float vi0 = wva.x * VX[v] + wva.y * VY[v];
    const float vi1 = wvb.x * VX[v] + wvb.y * VY[v];
#pragma unroll
    for (int st = 0; st < 3; ++st) {
      { f32x2 rv = {r0, r1}; *(f32x2*)(r6L + s * 36 + u0) = rv; }
      __builtin_amdgcn_wave_barrier();
      // two partial chains per row to halve FMA dependency latency
      float aA0 = sf0, aB0 = 0.f, aA1 = sf1, aB1 = 0.f;
      float pA0 = 0.f, pA1 = 0.f;
      const bool last = (v == 2 && st == 2);
#pragma unroll
      for (int kb = 0; kb < 8; ++kb) {
        const f32x4 r4 = *(const f32x4*)(r6L + s * 36 + kb * 4);
        float q0 = M0[kb][0] * r4[0] + M0[kb][1] * r4[1] +
                   M0[kb][2] * r4[2] + M0[kb][3] * r4[3];
        float q1 = M1[kb][0] * r4[0] + M1[kb][1] * r4[1] +
                   M1[kb][2] * r4[2] + M1[kb][3] * r4[3];
        if (kb & 1) { aB0 -= q0; aB1 -= q1; } else { aA0 -= q0; aA1 -= q1; }
        if (last) {
          const f32x4 g0 = *(const f32x4*)(WfbL + u0 * 36 + kb * 4);
          const f32x4 g1 = *(const f32x4*)(WfbL + u1 * 36 + kb * 4);
          pA0 += g0[0] * r4[0] + g0[1] * r4[1] + g0[2] * r4[2] + g0[3] * r4[3];
          pA1 += g1[0] * r4[0] + g1[1] * r4[1] + g1[2] * r4[2] + g1[3] * r4[3];
        }
      }
      __builtin_amdgcn_wave_barrier();
      if (last) { e0 = fabsf(sv0 - pA0); e1 = fabsf(sv1 - pA1); }
      y0 = fmaxf(aA0 + aB0, 0.f);
      y1 = fmaxf(aA1 + aB1, 0.f);
      r0 += 0.1f * (y0 - r0 + yb0 + vi0);
      r1 += 0.1f * (y1 - r1 + yb1 + vi1);
    }
  }

  // ---- feature = [y_ff | y_fb | r6 | |d|] into LDS (intra-wave) ----
  { f32x2 v = {y0, y1};   *(f32x2*)(ftL + s * 132 +       u0) = v; }
  { f32x2 v = {yb0, yb1}; *(f32x2*)(ftL + s * 132 + 32 +  u0) = v; }
  { f32x2 v = {r0, r1};   *(f32x2*)(ftL + s * 132 + 64 +  u0) = v; }
  { f32x2 v = {e0, e1};   *(f32x2*)(ftL + s * 132 + 96 +  u0) = v; }
  __builtin_amdgcn_wave_barrier();

  // ---- classifier layer 1 (f32, Wc1 from global; thread owns h = 4p..4p+3) ----
  f32x4 hacc = *(const f32x4*)(bc1 + 4 * p);
#pragma unroll 4
  for (int fb = 0; fb < 32; ++fb) {
    const f32x4 f4 = *(const f32x4*)(ftL + s * 132 + fb * 4);
#pragma unroll
    for (int hh = 0; hh < 4; ++hh) {
      const f32x4 w4 = *(const f32x4*)(Wc1 + (size_t)(4 * p + hh) * 128 + fb * 4);
      hacc[hh] += f4[0] * w4[0] + f4[1] * w4[1] + f4[2] * w4[2] + f4[3] * w4[3];
    }
  }
  f32x4 hg;
#pragma unroll
  for (int hh = 0; hh < 4; ++hh) {
    const float x = hacc[hh];
    hg[hh] = 0.5f * x * (1.0f + erff(x * 0.70710678118654752f));
  }
  *(f32x4*)(hLd + s * 68 + 4 * p) = hg;
  __builtin_amdgcn_wave_barrier();

  // ---- classifier layer 2: logits (lanes p<10) ----
  if (p < 10) {
    float acc = bc2[p];
#pragma unroll
    for (int hb = 0; hb < 16; ++hb) {
      const f32x4 h4 = *(const f32x4*)(hLd + s * 68 + hb * 4);
      const f32x4 w4 = *(const f32x4*)(Wc2 + (size_t)p * 64 + hb * 4);
      acc += h4[0] * w4[0] + h4[1] * w4[1] + h4[2] * w4[2] + h4[3] * w4[3];
    }
    out[(size_t)sg * 10 + p] = acc;
  }
}

extern "C" void kernel_launch(void* const* d_in, const int* in_sizes, int n_in,
                              void* d_out, int out_size, void* d_ws, size_t ws_size,
                              hipStream_t stream) {
  const float* img  = (const float*)d_in[0];
  const float* Wff  = (const float*)d_in[1];
  const float* Wfb  = (const float*)d_in[2];
  const float* Wvel = (const float*)d_in[3];
  const float* Wc1  = (const float*)d_in[4];
  const float* bc1  = (const float*)d_in[5];
  const float* Wc2  = (const float*)d_in[6];
  const float* bc2  = (const float*)d_in[7];
  float* out = (float*)d_out;
  const int B = in_sizes[0] / 784;     // 16384
  const int grid = B / 16;             // 1024 blocks, 16 samples each
  hipLaunchKernelGGL(mnist_dp, dim3(grid), dim3(256), 0, stream,
                     img, Wff, Wfb, Wvel, Wc1, bc1, Wc2, bc2, out);
}

// Round 7
// 97.079 us; speedup vs baseline: 1.0461x; 1.0461x over previous
//
#include <hip/hip_runtime.h>
#include <math.h>

typedef float f32x4 __attribute__((ext_vector_type(4)));
typedef float f32x2 __attribute__((ext_vector_type(2)));

#define DOT4(A, B) ((A)[0]*(B)[0] + (A)[1]*(B)[1] + (A)[2]*(B)[2] + (A)[3]*(B)[3])

// Data-parallel: thread = (sample, unit). 32 threads/sample, 8 samples/block,
// 2048 blocks. Cross-unit exchange = intra-wave LDS broadcast (sample = half-wave).
// No per-thread indexed arrays -> no scratch. M row lives in 8 named f32x4 regs.
__global__ __launch_bounds__(256) void mnist_dp2(
    const float* __restrict__ img, const float* __restrict__ Wff,
    const float* __restrict__ Wfb, const float* __restrict__ Wvel,
    const float* __restrict__ Wc1, const float* __restrict__ bc1,
    const float* __restrict__ Wc2, const float* __restrict__ bc2,
    float* __restrict__ out) {
  __shared__ float WffL[32 * 36];
  __shared__ float WfbL[32 * 36];
  __shared__ float Mds[32 * 36];
  __shared__ float snL[8 * 36];
  __shared__ float tdL[8 * 36];
  __shared__ float r6L[8 * 36];
  __shared__ float ftL[8 * 132];
  __shared__ float hLd[8 * 68];

  const int t = threadIdx.x;
  const int s = t >> 5, p = t & 31;       // sample-in-block, unit
  const int sg = blockIdx.x * 8 + s;

  // ---- taps for unit p (pos in [11.75, 771.25], never clipped; hi = lo+1) ----
  const float pos = 24.5f * (float)p + 11.75f;
  const int lo = (int)pos;
  const float w = pos - (float)lo;
  const int ta = (lo % 28) * 28 + lo / 28;
  const int tb = ((lo + 1) % 28) * 28 + (lo + 1) / 28;
  const float* im = img + (size_t)sg * 784;
  const float a0 = im[lo], a1 = im[lo + 1];     // sensory taps (near-sequential lines)
  const float c0 = im[ta], c1 = im[tb];         // topdown taps (transposed)
  const float2 wvp = ((const float2*)Wvel)[p];

  // ---- stage Wff/Wfb into LDS (stride 36 floats, 16B-aligned rows) ----
  {
    const int rj = t >> 3, c4 = (t & 7) * 4;
    *(f32x4*)(WffL + rj * 36 + c4) = *(const f32x4*)(Wff + rj * 32 + c4);
    *(f32x4*)(WfbL + rj * 36 + c4) = *(const f32x4*)(Wfb + rj * 32 + c4);
  }
  // interp results (own unit) -> LDS
  const float sv = (a0 + (a1 - a0) * w) * 80.0f;
  const float tv = (c0 + (c1 - c0) * w) * 40.0f;
  snL[s * 36 + p] = sv;
  tdL[s * 36 + p] = tv;
  __syncthreads();

  // ---- cooperative M = Wff @ Wfb  (M[i][k] = sum_j Wff[i][j]*Wfb[j][k]) ----
  {
    const int i = t >> 3, k0 = (t & 7) * 4;
    float m0 = 0.f, m1 = 0.f, m2 = 0.f, m3 = 0.f;
#pragma unroll
    for (int j = 0; j < 32; ++j) {
      const float a = WffL[i * 36 + j];
      const f32x4 w4 = *(const f32x4*)(WfbL + j * 36 + k0);
      m0 += a * w4[0]; m1 += a * w4[1]; m2 += a * w4[2]; m3 += a * w4[3];
    }
    f32x4 m = {m0, m1, m2, m3};
    *(f32x4*)(Mds + i * 36 + k0) = m;
  }
  __syncthreads();

  // ---- own M row into 8 NAMED f32x4 regs (32 VGPR, no arrays) ----
  const float* Mrow = Mds + p * 36;
  const f32x4 M0 = *(const f32x4*)(Mrow +  0);
  const f32x4 M1 = *(const f32x4*)(Mrow +  4);
  const f32x4 M2 = *(const f32x4*)(Mrow +  8);
  const f32x4 M3 = *(const f32x4*)(Mrow + 12);
  const f32x4 M4 = *(const f32x4*)(Mrow + 16);
  const f32x4 M5 = *(const f32x4*)(Mrow + 20);
  const f32x4 M6 = *(const f32x4*)(Mrow + 24);
  const f32x4 M7 = *(const f32x4*)(Mrow + 28);

  // ---- sff = Wff[p]·sens ; yfb = relu(Wfb[p]·td) ----
  float sf = 0.f, yb = 0.f;
#pragma unroll
  for (int jb = 0; jb < 8; ++jb) {
    const f32x4 s4 = *(const f32x4*)(snL + s * 36 + jb * 4);   // broadcast
    const f32x4 t4 = *(const f32x4*)(tdL + s * 36 + jb * 4);   // broadcast
    const f32x4 f4 = *(const f32x4*)(WffL + p * 36 + jb * 4);
    const f32x4 g4 = *(const f32x4*)(WfbL + p * 36 + jb * 4);
    sf += DOT4(f4, s4);
    yb += DOT4(g4, t4);
  }
  yb = fmaxf(yb, 0.f);

  // ---- recurrence: y = relu(sff - M·r6); r6 += 0.1*(-r6 + y + yfb + vin) ----
  float r = 0.f, y = 0.f, e = 0.f;
  const float VX[3] = {0.2f, 0.0f, 0.15f};
  const float VY[3] = {0.0f, 0.2f, 0.15f};
#pragma unroll
  for (int v = 0; v < 3; ++v) {
    const float vi = wvp.x * VX[v] + wvp.y * VY[v];
#pragma unroll
    for (int st = 0; st < 3; ++st) {
      r6L[s * 36 + p] = r;
      __builtin_amdgcn_wave_barrier();
      const f32x4 r40 = *(const f32x4*)(r6L + s * 36 +  0);    // broadcast reads
      const f32x4 r41 = *(const f32x4*)(r6L + s * 36 +  4);
      const f32x4 r42 = *(const f32x4*)(r6L + s * 36 +  8);
      const f32x4 r43 = *(const f32x4*)(r6L + s * 36 + 12);
      const f32x4 r44 = *(const f32x4*)(r6L + s * 36 + 16);
      const f32x4 r45 = *(const f32x4*)(r6L + s * 36 + 20);
      const f32x4 r46 = *(const f32x4*)(r6L + s * 36 + 24);
      const f32x4 r47 = *(const f32x4*)(r6L + s * 36 + 28);
      // two independent chains
      float accA = sf - DOT4(M0, r40) - DOT4(M2, r42) - DOT4(M4, r44) - DOT4(M6, r46);
      float accB =      DOT4(M1, r41) + DOT4(M3, r43) + DOT4(M5, r45) + DOT4(M7, r47);
      if (v == 2 && st == 2) {
        // d_p = sens_p - pred_p, pred_p = Wfb[p]·r6 (before update)
        float pa = 0.f, pb = 0.f;
        const float* gr = WfbL + p * 36;
        pa += DOT4((*(const f32x4*)(gr +  0)), r40);
        pb += DOT4((*(const f32x4*)(gr +  4)), r41);
        pa += DOT4((*(const f32x4*)(gr +  8)), r42);
        pb += DOT4((*(const f32x4*)(gr + 12)), r43);
        pa += DOT4((*(const f32x4*)(gr + 16)), r44);
        pb += DOT4((*(const f32x4*)(gr + 20)), r45);
        pa += DOT4((*(const f32x4*)(gr + 24)), r46);
        pb += DOT4((*(const f32x4*)(gr + 28)), r47);
        e = fabsf(sv - (pa + pb));
      }
      __builtin_amdgcn_wave_barrier();
      y = fmaxf(accA - accB, 0.f);
      r += 0.1f * (y - r + yb + vi);
    }
  }

  // ---- feature = [y_ff | y_fb | r6 | |d|] ----
  ftL[s * 132 +      p] = y;
  ftL[s * 132 + 32 + p] = yb;
  ftL[s * 132 + 64 + p] = r;
  ftL[s * 132 + 96 + p] = e;
  __builtin_amdgcn_wave_barrier();

  // ---- classifier layer 1: thread owns h = {2p, 2p+1} ----
  const f32x2 b2 = *(const f32x2*)(bc1 + 2 * p);
  float h0 = b2.x, h1 = b2.y;
  const float* w1a = Wc1 + (size_t)(2 * p) * 128;
  const float* w1b = w1a + 128;
#pragma unroll
  for (int fb = 0; fb < 32; ++fb) {
    const f32x4 f4 = *(const f32x4*)(ftL + s * 132 + fb * 4);  // broadcast
    const f32x4 wa = *(const f32x4*)(w1a + fb * 4);
    const f32x4 wb = *(const f32x4*)(w1b + fb * 4);
    h0 += DOT4(wa, f4);
    h1 += DOT4(wb, f4);
  }
  const float g0 = 0.5f * h0 * (1.0f + erff(h0 * 0.70710678118654752f));
  const float g1 = 0.5f * h1 * (1.0f + erff(h1 * 0.70710678118654752f));
  { f32x2 gv = {g0, g1}; *(f32x2*)(hLd + s * 68 + 2 * p) = gv; }
  __builtin_amdgcn_wave_barrier();

  // ---- classifier layer 2: logits (lanes p<10 per sample) ----
  if (p < 10) {
    float acc = bc2[p];
    const float* w2 = Wc2 + (size_t)p * 64;
#pragma unroll
    for (int hb = 0; hb < 16; ++hb) {
      const f32x4 h4 = *(const f32x4*)(hLd + s * 68 + hb * 4); // broadcast
      const f32x4 w4 = *(const f32x4*)(w2 + hb * 4);
      acc += DOT4(w4, h4);
    }
    out[(size_t)sg * 10 + p] = acc;
  }
}

extern "C" void kernel_launch(void* const* d_in, const int* in_sizes, int n_in,
                              void* d_out, int out_size, void* d_ws, size_t ws_size,
                              hipStream_t stream) {
  const float* img  = (const float*)d_in[0];
  const float* Wff  = (const float*)d_in[1];
  const float* Wfb  = (const float*)d_in[2];
  const float* Wvel = (const float*)d_in[3];
  const float* Wc1  = (const float*)d_in[4];
  const float* bc1  = (const float*)d_in[5];
  const float* Wc2  = (const float*)d_in[6];
  const float* bc2  = (const float*)d_in[7];
  float* out = (float*)d_out;
  const int B = in_sizes[0] / 784;     // 16384
  const int grid = B / 8;              // 2048 blocks, 8 samples each
  hipLaunchKernelGGL(mnist_dp2, dim3(grid), dim3(256), 0, stream,
                     img, Wff, Wfb, Wvel, Wc1, bc1, Wc2, bc2, out);
}

// Round 8
// 27.960 us; speedup vs baseline: 3.6321x; 3.4720x over previous
//
#include <hip/hip_runtime.h>
#include <math.h>

typedef float f32x4 __attribute__((ext_vector_type(4)));
typedef float f32x2 __attribute__((ext_vector_type(2)));

#define DOT4(A, B) ((A)[0]*(B)[0] + (A)[1]*(B)[1] + (A)[2]*(B)[2] + (A)[3]*(B)[3])

// Data-parallel: thread = (sample, unit) for the column phase; remapped to
// (f-quarter, h-unit) for classifier layer 1 so one Wc1 read serves 8 samples.
// 8 samples/block, 2048 blocks. LDS ~29 KB -> 5 blocks/CU.
__global__ __launch_bounds__(256, 4) void mnist_dp3(
    const float* __restrict__ img, const float* __restrict__ Wff,
    const float* __restrict__ Wfb, const float* __restrict__ Wvel,
    const float* __restrict__ Wc1, const float* __restrict__ bc1,
    const float* __restrict__ Wc2, const float* __restrict__ bc2,
    float* __restrict__ out) {
  __shared__ float WffL[32 * 36];
  __shared__ float WfbL[32 * 36];
  __shared__ float uSc[2048];          // phase A: Mds (1152 used); phase B: pLd (4*8*64)
  __shared__ float snL[8 * 36];
  __shared__ float tdL[8 * 36];
  __shared__ float r6L[8 * 36];
  __shared__ float ftL[8 * 132];
  __shared__ float hLd[8 * 68];
  __shared__ float Wc2L[10 * 68];

  const int t = threadIdx.x;
  const int s = t >> 5, p = t & 31;       // sample-in-block, unit
  const int sg = blockIdx.x * 8 + s;

  // ---- taps for unit p (pos in [11.75, 771.25], never clipped; hi = lo+1) ----
  const float pos = 24.5f * (float)p + 11.75f;
  const int lo = (int)pos;
  const float w = pos - (float)lo;
  const int ta = (lo % 28) * 28 + lo / 28;
  const int tb = ((lo + 1) % 28) * 28 + (lo + 1) / 28;
  const float* im = img + (size_t)sg * 784;
  const float a0 = im[lo], a1 = im[lo + 1];
  const float c0 = im[ta], c1 = im[tb];
  const float2 wvp = ((const float2*)Wvel)[p];

  // ---- stage Wff/Wfb (stride 36) and Wc2 (stride 68) into LDS ----
  {
    const int rj = t >> 3, c4 = (t & 7) * 4;
    *(f32x4*)(WffL + rj * 36 + c4) = *(const f32x4*)(Wff + rj * 32 + c4);
    *(f32x4*)(WfbL + rj * 36 + c4) = *(const f32x4*)(Wfb + rj * 32 + c4);
  }
  if (t < 160) {
    const int r2 = t >> 4, c2 = (t & 15) * 4;
    *(f32x4*)(Wc2L + r2 * 68 + c2) = *(const f32x4*)(Wc2 + r2 * 64 + c2);
  }
  const float sv = (a0 + (a1 - a0) * w) * 80.0f;
  const float tv = (c0 + (c1 - c0) * w) * 40.0f;
  snL[s * 36 + p] = sv;
  tdL[s * 36 + p] = tv;
  __syncthreads();

  // ---- cooperative M = Wff @ Wfb -> uSc (reads are few-address, cheap) ----
  {
    const int i = t >> 3, k0 = (t & 7) * 4;
    float m0 = 0.f, m1 = 0.f, m2 = 0.f, m3 = 0.f;
#pragma unroll
    for (int j = 0; j < 32; ++j) {
      const float a = WffL[i * 36 + j];
      const f32x4 w4 = *(const f32x4*)(WfbL + j * 36 + k0);
      m0 += a * w4[0]; m1 += a * w4[1]; m2 += a * w4[2]; m3 += a * w4[3];
    }
    f32x4 m = {m0, m1, m2, m3};
    *(f32x4*)(uSc + i * 36 + k0) = m;
  }
  __syncthreads();

  // ---- own M row into 8 NAMED f32x4 regs ----
  const float* Mrow = uSc + p * 36;
  const f32x4 M0 = *(const f32x4*)(Mrow +  0);
  const f32x4 M1 = *(const f32x4*)(Mrow +  4);
  const f32x4 M2 = *(const f32x4*)(Mrow +  8);
  const f32x4 M3 = *(const f32x4*)(Mrow + 12);
  const f32x4 M4 = *(const f32x4*)(Mrow + 16);
  const f32x4 M5 = *(const f32x4*)(Mrow + 20);
  const f32x4 M6 = *(const f32x4*)(Mrow + 24);
  const f32x4 M7 = *(const f32x4*)(Mrow + 28);

  // ---- sff = Wff[p]·sens ; yfb = relu(Wfb[p]·td) ----
  float sf = 0.f, yb = 0.f;
#pragma unroll
  for (int jb = 0; jb < 8; ++jb) {
    const f32x4 s4 = *(const f32x4*)(snL + s * 36 + jb * 4);
    const f32x4 t4 = *(const f32x4*)(tdL + s * 36 + jb * 4);
    const f32x4 f4 = *(const f32x4*)(WffL + p * 36 + jb * 4);
    const f32x4 g4 = *(const f32x4*)(WfbL + p * 36 + jb * 4);
    sf += DOT4(f4, s4);
    yb += DOT4(g4, t4);
  }
  yb = fmaxf(yb, 0.f);

  // ---- recurrence: y = relu(sff - M·r6); r6 += 0.1*(-r6 + y + yfb + vin) ----
  float r = 0.f, y = 0.f, e = 0.f;
  const float VX[3] = {0.2f, 0.0f, 0.15f};
  const float VY[3] = {0.0f, 0.2f, 0.15f};
#pragma unroll
  for (int v = 0; v < 3; ++v) {
    const float vi = wvp.x * VX[v] + wvp.y * VY[v];
#pragma unroll
    for (int st = 0; st < 3; ++st) {
      r6L[s * 36 + p] = r;
      __builtin_amdgcn_wave_barrier();
      const f32x4 r40 = *(const f32x4*)(r6L + s * 36 +  0);
      const f32x4 r41 = *(const f32x4*)(r6L + s * 36 +  4);
      const f32x4 r42 = *(const f32x4*)(r6L + s * 36 +  8);
      const f32x4 r43 = *(const f32x4*)(r6L + s * 36 + 12);
      const f32x4 r44 = *(const f32x4*)(r6L + s * 36 + 16);
      const f32x4 r45 = *(const f32x4*)(r6L + s * 36 + 20);
      const f32x4 r46 = *(const f32x4*)(r6L + s * 36 + 24);
      const f32x4 r47 = *(const f32x4*)(r6L + s * 36 + 28);
      float accA = sf - DOT4(M0, r40) - DOT4(M2, r42) - DOT4(M4, r44) - DOT4(M6, r46);
      float accB =      DOT4(M1, r41) + DOT4(M3, r43) + DOT4(M5, r45) + DOT4(M7, r47);
      if (v == 2 && st == 2) {
        float pa = 0.f, pb = 0.f;
        const float* gr = WfbL + p * 36;
        pa += DOT4((*(const f32x4*)(gr +  0)), r40);
        pb += DOT4((*(const f32x4*)(gr +  4)), r41);
        pa += DOT4((*(const f32x4*)(gr +  8)), r42);
        pb += DOT4((*(const f32x4*)(gr + 12)), r43);
        pa += DOT4((*(const f32x4*)(gr + 16)), r44);
        pb += DOT4((*(const f32x4*)(gr + 20)), r45);
        pa += DOT4((*(const f32x4*)(gr + 24)), r46);
        pb += DOT4((*(const f32x4*)(gr + 28)), r47);
        e = fabsf(sv - (pa + pb));
      }
      __builtin_amdgcn_wave_barrier();
      y = fmaxf(accA - accB, 0.f);
      r += 0.1f * (y - r + yb + vi);
    }
  }

  // ---- feature = [y_ff | y_fb | r6 | |d|] ----
  ftL[s * 132 +      p] = y;
  ftL[s * 132 + 32 + p] = yb;
  ftL[s * 132 + 64 + p] = r;
  ftL[s * 132 + 96 + p] = e;
  __syncthreads();   // features + uSc(M) consumers all done -> safe to reuse uSc

  // ---- classifier L1 pass 1: wave q = f-quarter, lane o = h-unit ----
  // one Wc1 row-chunk read (global, L1-resident) serves all 8 samples.
  {
    const int q = t >> 6, o = t & 63;
    const float* wrow = Wc1 + (size_t)o * 128 + q * 32;
    float acc[8] = {0.f, 0.f, 0.f, 0.f, 0.f, 0.f, 0.f, 0.f};
#pragma unroll
    for (int fb = 0; fb < 8; ++fb) {
      const f32x4 w4 = *(const f32x4*)(wrow + fb * 4);
#pragma unroll
      for (int ss = 0; ss < 8; ++ss) {
        const f32x4 f4 = *(const f32x4*)(ftL + ss * 132 + q * 32 + fb * 4); // broadcast
        acc[ss] += DOT4(w4, f4);
      }
    }
#pragma unroll
    for (int ss = 0; ss < 8; ++ss)
      uSc[q * 512 + ss * 64 + o] = acc[ss];
  }
  __syncthreads();

  // ---- classifier L1 pass 2: reduce 4 partials, bias + gelu ----
  {
    const int o = t & 63, s2 = t >> 6;       // samples s2 and s2+4
    const float b = bc1[o];
    const float hA = b + uSc[s2 * 64 + o]        + uSc[512 + s2 * 64 + o]
                       + uSc[1024 + s2 * 64 + o] + uSc[1536 + s2 * 64 + o];
    const int s3 = s2 + 4;
    const float hB = b + uSc[s3 * 64 + o]        + uSc[512 + s3 * 64 + o]
                       + uSc[1024 + s3 * 64 + o] + uSc[1536 + s3 * 64 + o];
    hLd[s2 * 68 + o] = 0.5f * hA * (1.0f + erff(hA * 0.70710678118654752f));
    hLd[s3 * 68 + o] = 0.5f * hB * (1.0f + erff(hB * 0.70710678118654752f));
  }
  __syncthreads();

  // ---- classifier L2: logits ----
  if (p < 10) {
    float acc = bc2[p];
    const float* w2 = Wc2L + p * 68;
#pragma unroll
    for (int hb = 0; hb < 16; ++hb) {
      const f32x4 h4 = *(const f32x4*)(hLd + s * 68 + hb * 4);  // broadcast
      const f32x4 w4 = *(const f32x4*)(w2 + hb * 4);
      acc += DOT4(w4, h4);
    }
    out[(size_t)sg * 10 + p] = acc;
  }
}

extern "C" void kernel_launch(void* const* d_in, const int* in_sizes, int n_in,
                              void* d_out, int out_size, void* d_ws, size_t ws_size,
                              hipStream_t stream) {
  const float* img  = (const float*)d_in[0];
  const float* Wff  = (const float*)d_in[1];
  const float* Wfb  = (const float*)d_in[2];
  const float* Wvel = (const float*)d_in[3];
  const float* Wc1  = (const float*)d_in[4];
  const float* bc1  = (const float*)d_in[5];
  const float* Wc2  = (const float*)d_in[6];
  const float* bc2  = (const float*)d_in[7];
  float* out = (float*)d_out;
  const int B = in_sizes[0] / 784;     // 16384
  const int grid = B / 8;              // 2048 blocks, 8 samples each
  hipLaunchKernelGGL(mnist_dp3, dim3(grid), dim3(256), 0, stream,
                     img, Wff, Wfb, Wvel, Wc1, bc1, Wc2, bc2, out);
}